// Round 2
// baseline (318.818 us; speedup 1.0000x reference)
//
#include <hip/hip_runtime.h>
#include <stdint.h>

typedef __bf16 bf16x8 __attribute__((ext_vector_type(8)));
typedef float  f32x4  __attribute__((ext_vector_type(4)));

static constexpr int Bn = 32, Cn = 128, Hn = 64, Wn = 64, HWn = 4096;
static constexpr size_t OFF_XT    = 0;                       // 33,554,432 B (bf16 x, chunk-major NHWC)
static constexpr size_t OFF_WF    = 33554432;                // 221,184 B (B-fragment-ordered weights)
static constexpr size_t OFF_IDX   = 33775616;                // 1,536 B
static constexpr size_t OFF_M     = 33777152;                // 33,554,432 B (median result, bf16, NCHW)
static constexpr size_t OFF_STATS = 67331584;                // 1,024 B
static constexpr size_t OFF_BN    = 67332608;                // 1,024 B

__device__ __forceinline__ unsigned short f32_to_bf16(float f) {
    union { float f; unsigned u; } v; v.f = f;
    unsigned u = v.u;
    return (unsigned short)((u + 0x7FFFu + ((u >> 16) & 1u)) >> 16);
}
__device__ __forceinline__ float bf16_to_f32(unsigned short h) {
    union { unsigned u; float f; } v; v.u = ((unsigned)h) << 16;
    return v.f;
}
__device__ __forceinline__ float bf_lo(unsigned w) {
    union { unsigned u; float f; } v; v.u = w << 16; return v.f;
}
__device__ __forceinline__ float bf_hi(unsigned w) {
    union { unsigned u; float f; } v; v.u = w & 0xffff0000u; return v.f;
}
__device__ __forceinline__ float med3(float z0, float z1, float z2) {
    float lo = fminf(z0, z1), hi = fmaxf(z0, z1);
    return fmaxf(lo, fminf(hi, z2));
}

// ---- K0: x NCHW fp32 -> xT[b][q][y][x][32ci] bf16 (chunk-major NHWC) ----
__global__ __launch_bounds__(256) void k_transpose(const float* __restrict__ x,
                                                   unsigned short* __restrict__ xT) {
    __shared__ __align__(16) unsigned short sm[256 * 40];
    int blk = blockIdx.x;                 // b*64 + q*16 + pt
    int pt = blk & 15, q = (blk >> 4) & 3, b = blk >> 6;
    int p0 = pt * 256;
    int t = threadIdx.x;
    const float* xp = x + ((size_t)(b * Cn + q * 32) * HWn) + p0 + t;
#pragma unroll
    for (int cil = 0; cil < 32; ++cil)
        sm[t * 40 + cil] = f32_to_bf16(xp[(size_t)cil * HWn]);
    __syncthreads();
    uint4* dst = (uint4*)(xT + ((size_t)(b * 4 + q) * HWn + p0) * 32);
#pragma unroll
    for (int pass = 0; pass < 4; ++pass) {
        int pix = pass * 64 + (t >> 2);
        int ch  = t & 3;
        dst[pix * 4 + ch] = *(const uint4*)(&sm[pix * 40 + ch * 8]);
    }
}

// ---- K1a: recover idx[j][c] from one-hot hs (3,32,128) ----
__global__ void k_idx(const float* __restrict__ hs, int* __restrict__ idx) {
    int t = blockIdx.x * 256 + threadIdx.x;
    if (t >= 384) return;
    int j = t >> 7, c = t & 127;
    int found = 0;
    for (int d = 0; d < 32; ++d)
        if (hs[(j * 32 + d) * 128 + c] > 0.5f) found = d;
    idx[t] = found;
}

// ---- K1b: sketched weights in MFMA B-fragment order ----
// layout: f = ((q*9+t)*6+nt)*512 + lane*8 + jj holds B[k=(lane>>4)*8+jj][n=nt*16+(lane&15)]
__global__ __launch_bounds__(256) void k_wsk(const float* __restrict__ w2,
                                             const float* __restrict__ hs,
                                             const float* __restrict__ ss,
                                             unsigned short* __restrict__ wf) {
    int f = blockIdx.x * 256 + threadIdx.x;   // 110592 total
    int jj   = f & 7;
    int lane = (f >> 3) & 63;
    int nt   = (f >> 9) % 6;
    int qt   = f / (512 * 6);
    int t    = qt % 9;
    int q    = qt / 9;
    int k  = ((lane >> 4) << 3) + jj;
    int ci = q * 32 + k;
    int n  = nt * 16 + (lane & 15);
    int j = n >> 5, d = n & 31;
    float sum = 0.f;
    for (int c = 0; c < 128; ++c) {
        float g = hs[(j * 32 + d) * 128 + c];
        if (g != 0.f) sum += g * ss[j * 128 + c] * w2[(c * 128 + ci) * 9 + t];
    }
    wf[f] = f32_to_bf16(sum);
}

// ---- K2: conv(96ch) + unsketch + median3 + fused BN stats -> m (bf16, NCHW) ----
// grid 512 = b*16 + tile; tile = 4 rows x 64 cols; wave w owns row py=w.
// launch_bounds(256,2): full 256-reg budget -> no spill of prefetch buffers.
// Async-split staging (T14) + B-fragment double-buffer (1 tap ahead).
// Epilogue: y stored [ch][264] -> median gather via dense ds_read_b128,
// coalesced dwordx4 m stores, per-channel stats via 5-level half-wave shfl.
__global__ __launch_bounds__(256, 2) void k_conv(const unsigned short* __restrict__ xT,
                                                 const unsigned short* __restrict__ wf,
                                                 const int* __restrict__ idx,
                                                 const float* __restrict__ ss,
                                                 unsigned short* __restrict__ m_out,
                                                 float* __restrict__ stats) {
    // staging 396*40 = 15840 ushorts, aliased with y tile [96][264] = 25344 ushorts
    __shared__ __align__(16) unsigned short sm[25344];
    __shared__ int   idx_sh[384];
    __shared__ float ss_sh[384];
    int tid  = threadIdx.x;
    int blk  = blockIdx.x;
    int tile = blk & 15, b = blk >> 4;
    int ty0  = tile * 4;
    int wv   = tid >> 6, lane = tid & 63;
    int quad = lane >> 4, l15 = lane & 15;

    for (int i = tid; i < 384; i += 256) { idx_sh[i] = idx[i]; ss_sh[i] = ss[i]; }

    // 396 records x 4 chunks = 1584 uint4 chunks; 7 slots per thread
    int goff[7], loff[7];
#pragma unroll
    for (int i = 0; i < 7; ++i) {
        int k = tid + i * 256;
        if (k < 1584) {
            int r = k >> 2, ch = k & 3;
            int hy = r / 66, hx = r - hy * 66;
            int gy = ty0 + hy - 1, gx = hx - 1;
            loff[i] = r * 40 + ch * 8;
            goff[i] = (gy >= 0 && gy < 64 && gx >= 0 && gx < 64)
                    ? ((gy * 64 + gx) * 32 + ch * 8) : -1;
        } else { loff[i] = -1; goff[i] = -1; }
    }

    f32x4 acc[4][6];
#pragma unroll
    for (int a = 0; a < 4; ++a)
#pragma unroll
        for (int nb = 0; nb < 6; ++nb) acc[a][nb] = (f32x4){0.f, 0.f, 0.f, 0.f};

    const uint4 z4 = {0u, 0u, 0u, 0u};
    uint4 h[7];

    // prologue: stage q=0 synchronously
    {
        const unsigned short* xq = xT + (size_t)(b * 4) * (HWn * 32);
#pragma unroll
        for (int i = 0; i < 7; ++i)
            if (loff[i] >= 0) {
                uint4 v = (goff[i] >= 0) ? *(const uint4*)(xq + goff[i]) : z4;
                *(uint4*)(&sm[loff[i]]) = v;
            }
    }
    __syncthreads();

    const unsigned short* wl = wf + lane * 8;

    for (int q = 0; q < 4; ++q) {
        // T14: issue next-q halo loads; latency hides under 36 taps of MFMA
        if (q < 3) {
            const unsigned short* xq = xT + (size_t)(b * 4 + q + 1) * (HWn * 32);
#pragma unroll
            for (int i = 0; i < 7; ++i)
                h[i] = (loff[i] >= 0 && goff[i] >= 0) ? *(const uint4*)(xq + goff[i]) : z4;
        }
        const unsigned short* wq = wl + (size_t)(q * 54) * 512;
        bf16x8 bfr[2][6];
#pragma unroll
        for (int nb = 0; nb < 6; ++nb) bfr[0][nb] = *(const bf16x8*)(wq + nb * 512);
#pragma unroll
        for (int tp = 0; tp < 9; ++tp) {
            int cur = tp & 1;
            if (tp < 8) {   // prefetch next tap's B fragments (L2) under current MFMAs
                const unsigned short* wb = wq + (size_t)((tp + 1) * 6) * 512;
#pragma unroll
                for (int nb = 0; nb < 6; ++nb)
                    bfr[cur ^ 1][nb] = *(const bf16x8*)(wb + nb * 512);
            }
            int dy = tp / 3, dx = tp % 3;
            bf16x8 afr[4];
#pragma unroll
            for (int mq = 0; mq < 4; ++mq) {
                int off = ((wv + dy) * 66 + mq * 16 + l15 + dx) * 40 + quad * 8;
                afr[mq] = *(const bf16x8*)(&sm[off]);
            }
#pragma unroll
            for (int mq = 0; mq < 4; ++mq)
#pragma unroll
                for (int nb = 0; nb < 6; ++nb)
                    acc[mq][nb] = __builtin_amdgcn_mfma_f32_16x16x32_bf16(afr[mq], bfr[cur][nb], acc[mq][nb], 0, 0, 0);
        }
        __syncthreads();
        if (q < 3) {
#pragma unroll
            for (int i = 0; i < 7; ++i)
                if (loff[i] >= 0) *(uint4*)(&sm[loff[i]]) = h[i];
            __syncthreads();
        }
    }

    // y-dump: channel-major [ch][264] so median gather is vectorizable over pixels
#pragma unroll
    for (int mq = 0; mq < 4; ++mq)
#pragma unroll
        for (int nb = 0; nb < 6; ++nb) {
            int ch = nb * 16 + l15;
            int px = wv * 64 + mq * 16 + quad * 4;
            ushort4 v;
            v.x = f32_to_bf16(acc[mq][nb][0]);
            v.y = f32_to_bf16(acc[mq][nb][1]);
            v.z = f32_to_bf16(acc[mq][nb][2]);
            v.w = f32_to_bf16(acc[mq][nb][3]);
            *(ushort4*)(&sm[ch * 264 + px]) = v;
        }
    __syncthreads();

    // median-of-3 (8 px per b128 read) + coalesced store + fused per-channel stats
    int half = lane >> 5, p8 = lane & 31;
    unsigned short* mpb = m_out + (size_t)b * Cn * HWn + tile * 256 + p8 * 8;
#pragma unroll 2
    for (int i = 0; i < 16; ++i) {
        int c = wv * 32 + i * 2 + half;        // 32 lanes share one channel
        int r0 = idx_sh[c], r1 = 32 + idx_sh[128 + c], r2 = 64 + idx_sh[256 + c];
        float sg0 = ss_sh[c], sg1 = ss_sh[128 + c], sg2 = ss_sh[256 + c];
        uint4 w0 = *(const uint4*)(&sm[r0 * 264 + p8 * 8]);
        uint4 w1 = *(const uint4*)(&sm[r1 * 264 + p8 * 8]);
        uint4 w2v = *(const uint4*)(&sm[r2 * 264 + p8 * 8]);
        const unsigned* u0 = (const unsigned*)&w0;
        const unsigned* u1 = (const unsigned*)&w1;
        const unsigned* u2 = (const unsigned*)&w2v;
        uint4 R;
        unsigned* rw = (unsigned*)&R;
        float s = 0.f, s2 = 0.f;
#pragma unroll
        for (int e = 0; e < 4; ++e) {
            float mlo = med3(sg0 * bf_lo(u0[e]), sg1 * bf_lo(u1[e]), sg2 * bf_lo(u2[e]));
            float mhi = med3(sg0 * bf_hi(u0[e]), sg1 * bf_hi(u1[e]), sg2 * bf_hi(u2[e]));
            s  += mlo + mhi;
            s2 += mlo * mlo + mhi * mhi;
            rw[e] = (unsigned)f32_to_bf16(mlo) | ((unsigned)f32_to_bf16(mhi) << 16);
        }
        *(uint4*)(mpb + (size_t)c * HWn) = R;
#pragma unroll
        for (int o = 16; o > 0; o >>= 1) { s += __shfl_xor(s, o); s2 += __shfl_xor(s2, o); }
        if ((lane & 31) == 0) { atomicAdd(&stats[c], s); atomicAdd(&stats[128 + c], s2); }
    }
}

// ---- K3b: finalize BN coefficients ----
__global__ void k_bn(const float* __restrict__ stats, const float* __restrict__ gamma,
                     const float* __restrict__ beta, float* __restrict__ bn) {
    int c = threadIdx.x;
    if (c < 128) {
        const float N = 131072.f;
        float mean = stats[c] / N;
        float var  = stats[128 + c] / N - mean * mean;
        float sc   = gamma[c] * rsqrtf(var + 1e-5f);
        bn[c] = sc;
        bn[128 + c] = beta[c] - mean * sc;
    }
}

// ---- K4: out = relu(m*sc+sh) + x ----
__global__ __launch_bounds__(256) void k_apply(const unsigned short* __restrict__ m,
                                               const float* __restrict__ x,
                                               const float* __restrict__ bn,
                                               float* __restrict__ out) {
    int i4 = blockIdx.x * 256 + threadIdx.x;      // 4,194,304 groups of 4
    size_t base = (size_t)i4 * 4;
    int c = (int)((base >> 12) & 127);
    float sc = bn[c], sh = bn[128 + c];
    ushort4 mv = ((const ushort4*)m)[i4];
    float4  xv = ((const float4*)x)[i4];
    float4 o;
    o.x = fmaxf(bf16_to_f32(mv.x) * sc + sh, 0.f) + xv.x;
    o.y = fmaxf(bf16_to_f32(mv.y) * sc + sh, 0.f) + xv.y;
    o.z = fmaxf(bf16_to_f32(mv.z) * sc + sh, 0.f) + xv.z;
    o.w = fmaxf(bf16_to_f32(mv.w) * sc + sh, 0.f) + xv.w;
    ((float4*)out)[i4] = o;
}

extern "C" void kernel_launch(void* const* d_in, const int* in_sizes, int n_in,
                              void* d_out, int out_size, void* d_ws, size_t ws_size,
                              hipStream_t stream) {
    const float* x      = (const float*)d_in[0];
    const float* w2     = (const float*)d_in[2];
    const float* gamma2 = (const float*)d_in[5];
    const float* beta2  = (const float*)d_in[6];
    const float* hs     = (const float*)d_in[7];
    const float* ss     = (const float*)d_in[8];
    float* out = (float*)d_out;

    char* ws = (char*)d_ws;
    unsigned short* xT  = (unsigned short*)(ws + OFF_XT);
    unsigned short* wfp = (unsigned short*)(ws + OFF_WF);
    int*            idp = (int*)(ws + OFF_IDX);
    unsigned short* mp  = (unsigned short*)(ws + OFF_M);
    float*          st  = (float*)(ws + OFF_STATS);
    float*          bnp = (float*)(ws + OFF_BN);

    hipMemsetAsync(st, 0, 1024, stream);
    k_transpose<<<2048, 256, 0, stream>>>(x, xT);
    k_idx<<<2, 256, 0, stream>>>(hs, idp);
    k_wsk<<<432, 256, 0, stream>>>(w2, hs, ss, wfp);
    k_conv<<<512, 256, 0, stream>>>(xT, wfp, idp, ss, mp, st);
    k_bn<<<1, 128, 0, stream>>>(st, gamma2, beta2, bnp);
    k_apply<<<16384, 256, 0, stream>>>(mp, x, bnp, out);
}

// Round 3
// 301.364 us; speedup vs baseline: 1.0579x; 1.0579x over previous
//
#include <hip/hip_runtime.h>
#include <stdint.h>

typedef __bf16 bf16x8 __attribute__((ext_vector_type(8)));
typedef float  f32x4  __attribute__((ext_vector_type(4)));

static constexpr int Bn = 32, Cn = 128, Hn = 64, Wn = 64, HWn = 4096;
static constexpr size_t OFF_XT    = 0;                       // 33,554,432 B (bf16 x, chunk-major NHWC)
static constexpr size_t OFF_WF    = 33554432;                // 221,184 B (B-fragment-ordered weights)
static constexpr size_t OFF_IDX   = 33775616;                // 1,536 B
static constexpr size_t OFF_M     = 33777152;                // 33,554,432 B (median result, bf16, NCHW)
static constexpr size_t OFF_STATS = 67331584;                // 1,024 B

__device__ __forceinline__ unsigned short f32_to_bf16(float f) {
    union { float f; unsigned u; } v; v.f = f;
    unsigned u = v.u;
    return (unsigned short)((u + 0x7FFFu + ((u >> 16) & 1u)) >> 16);
}
__device__ __forceinline__ float bf16_to_f32(unsigned short h) {
    union { unsigned u; float f; } v; v.u = ((unsigned)h) << 16;
    return v.f;
}
__device__ __forceinline__ float bf_lo(unsigned w) {
    union { unsigned u; float f; } v; v.u = w << 16; return v.f;
}
__device__ __forceinline__ float bf_hi(unsigned w) {
    union { unsigned u; float f; } v; v.u = w & 0xffff0000u; return v.f;
}
__device__ __forceinline__ float med3(float z0, float z1, float z2) {
    float lo = fminf(z0, z1), hi = fmaxf(z0, z1);
    return fmaxf(lo, fminf(hi, z2));
}

// ---- K0: x NCHW fp32 -> xT[b][q][y][x][32ci] bf16 (chunk-major NHWC) ----
__global__ __launch_bounds__(256) void k_transpose(const float* __restrict__ x,
                                                   unsigned short* __restrict__ xT) {
    __shared__ __align__(16) unsigned short sm[256 * 40];
    int blk = blockIdx.x;                 // b*64 + q*16 + pt
    int pt = blk & 15, q = (blk >> 4) & 3, b = blk >> 6;
    int p0 = pt * 256;
    int t = threadIdx.x;
    const float* xp = x + ((size_t)(b * Cn + q * 32) * HWn) + p0 + t;
#pragma unroll
    for (int cil = 0; cil < 32; ++cil)
        sm[t * 40 + cil] = f32_to_bf16(xp[(size_t)cil * HWn]);
    __syncthreads();
    uint4* dst = (uint4*)(xT + ((size_t)(b * 4 + q) * HWn + p0) * 32);
#pragma unroll
    for (int pass = 0; pass < 4; ++pass) {
        int pix = pass * 64 + (t >> 2);
        int ch  = t & 3;
        dst[pix * 4 + ch] = *(const uint4*)(&sm[pix * 40 + ch * 8]);
    }
}

// ---- K1: sketched weights in MFMA B-fragment order; block 432 recovers idx ----
// layout: f = ((q*9+t)*6+nt)*512 + lane*8 + jj holds B[k=(lane>>4)*8+jj][n=nt*16+(lane&15)]
__global__ __launch_bounds__(256) void k_wsk(const float* __restrict__ w2,
                                             const float* __restrict__ hs,
                                             const float* __restrict__ ss,
                                             unsigned short* __restrict__ wf,
                                             int* __restrict__ idx) {
    if (blockIdx.x == 432) {               // fused k_idx
        for (int t = threadIdx.x; t < 384; t += 256) {
            int j = t >> 7, c = t & 127;
            int found = 0;
            for (int d = 0; d < 32; ++d)
                if (hs[(j * 32 + d) * 128 + c] > 0.5f) found = d;
            idx[t] = found;
        }
        return;
    }
    int f = blockIdx.x * 256 + threadIdx.x;   // 110592 total
    int jj   = f & 7;
    int lane = (f >> 3) & 63;
    int nt   = (f >> 9) % 6;
    int qt   = f / (512 * 6);
    int t    = qt % 9;
    int q    = qt / 9;
    int k  = ((lane >> 4) << 3) + jj;
    int ci = q * 32 + k;
    int n  = nt * 16 + (lane & 15);
    int j = n >> 5, d = n & 31;
    float sum = 0.f;
    for (int c = 0; c < 128; ++c) {
        float g = hs[(j * 32 + d) * 128 + c];
        if (g != 0.f) sum += g * ss[j * 128 + c] * w2[(c * 128 + ci) * 9 + t];
    }
    wf[f] = f32_to_bf16(sum);
}

// ---- K2: conv(96ch) + unsketch + median3 + fused BN stats -> m (bf16, NCHW) ----
// grid 512 = b*16 + tile; tile = 4 rows x 64 cols; wave w owns row py=w.
// Main loop is the verified round-0 structure (84 VGPR, no spill). Epilogue:
// y stored channel-major [96][264] so median gather is ds_read_b128-dense,
// m stores are dwordx4-coalesced, BN stats fused via half-wave shfl + atomics.
__global__ __launch_bounds__(256, 2) void k_conv(const unsigned short* __restrict__ xT,
                                                 const unsigned short* __restrict__ wf,
                                                 const int* __restrict__ idx,
                                                 const float* __restrict__ ss,
                                                 unsigned short* __restrict__ m_out,
                                                 float* __restrict__ stats) {
    // staging 396*40 = 15840 ushorts, aliased with y tile [96][264] = 25344 ushorts
    __shared__ __align__(16) unsigned short sm[25344];
    __shared__ int   idx_sh[384];
    __shared__ float ss_sh[384];
    int tid  = threadIdx.x;
    int blk  = blockIdx.x;
    int tile = blk & 15, b = blk >> 4;
    int ty0  = tile * 4;
    int wv   = tid >> 6, lane = tid & 63;
    int quad = lane >> 4, l15 = lane & 15;

    for (int i = tid; i < 384; i += 256) { idx_sh[i] = idx[i]; ss_sh[i] = ss[i]; }

    f32x4 acc[4][6];
#pragma unroll
    for (int a = 0; a < 4; ++a)
#pragma unroll
        for (int nb = 0; nb < 6; ++nb) acc[a][nb] = (f32x4){0.f, 0.f, 0.f, 0.f};

    const unsigned short* wl = wf + lane * 8;

    for (int q = 0; q < 4; ++q) {
        __syncthreads();
        // stage halo: 396 records (6 rows x 66 cols) of 32 ci (64 B each)
#pragma unroll
        for (int pass = 0; pass < 2; ++pass) {
            int r = tid + pass * 256;
            if (r < 396) {
                int hy = r / 66, hx = r - hy * 66;
                int gy = ty0 + hy - 1, gx = hx - 1;
                uint4* dst = (uint4*)(&sm[r * 40]);
                if (gy >= 0 && gy < 64 && gx >= 0 && gx < 64) {
                    const uint4* src = (const uint4*)(xT + ((size_t)(b * 4 + q) * HWn + gy * 64 + gx) * 32);
                    dst[0] = src[0]; dst[1] = src[1]; dst[2] = src[2]; dst[3] = src[3];
                } else {
                    uint4 z = {0u, 0u, 0u, 0u};
                    dst[0] = z; dst[1] = z; dst[2] = z; dst[3] = z;
                }
            }
        }
        __syncthreads();
#pragma unroll
        for (int tp = 0; tp < 9; ++tp) {
            int dy = tp / 3, dx = tp % 3;
            bf16x8 bfr[6];
            const unsigned short* wb = wl + (size_t)((q * 9 + tp) * 6) * 512;
#pragma unroll
            for (int nb = 0; nb < 6; ++nb)
                bfr[nb] = *(const bf16x8*)(wb + nb * 512);
            bf16x8 afr[4];
#pragma unroll
            for (int mq = 0; mq < 4; ++mq) {
                int off = ((wv + dy) * 66 + mq * 16 + l15 + dx) * 40 + quad * 8;
                afr[mq] = *(const bf16x8*)(&sm[off]);
            }
#pragma unroll
            for (int mq = 0; mq < 4; ++mq)
#pragma unroll
                for (int nb = 0; nb < 6; ++nb)
                    acc[mq][nb] = __builtin_amdgcn_mfma_f32_16x16x32_bf16(afr[mq], bfr[nb], acc[mq][nb], 0, 0, 0);
        }
    }
    __syncthreads();
    // y-dump: channel-major [ch][264] so the median gather vectorizes over pixels
#pragma unroll
    for (int mq = 0; mq < 4; ++mq)
#pragma unroll
        for (int nb = 0; nb < 6; ++nb) {
            int ch = nb * 16 + l15;
            int px = wv * 64 + mq * 16 + quad * 4;
            ushort4 v;
            v.x = f32_to_bf16(acc[mq][nb][0]);
            v.y = f32_to_bf16(acc[mq][nb][1]);
            v.z = f32_to_bf16(acc[mq][nb][2]);
            v.w = f32_to_bf16(acc[mq][nb][3]);
            *(ushort4*)(&sm[ch * 264 + px]) = v;
        }
    __syncthreads();
    // median-of-3 (8 px per b128 read) + coalesced store + fused per-channel stats
    int half = lane >> 5, p8 = lane & 31;
    unsigned short* mpb = m_out + (size_t)b * Cn * HWn + tile * 256 + p8 * 8;
#pragma unroll 2
    for (int i = 0; i < 16; ++i) {
        int c = wv * 32 + i * 2 + half;        // 32 lanes share one channel
        int r0 = idx_sh[c], r1 = 32 + idx_sh[128 + c], r2 = 64 + idx_sh[256 + c];
        float sg0 = ss_sh[c], sg1 = ss_sh[128 + c], sg2 = ss_sh[256 + c];
        uint4 w0 = *(const uint4*)(&sm[r0 * 264 + p8 * 8]);
        uint4 w1 = *(const uint4*)(&sm[r1 * 264 + p8 * 8]);
        uint4 w2v = *(const uint4*)(&sm[r2 * 264 + p8 * 8]);
        const unsigned* u0 = (const unsigned*)&w0;
        const unsigned* u1 = (const unsigned*)&w1;
        const unsigned* u2 = (const unsigned*)&w2v;
        uint4 R;
        unsigned* rw = (unsigned*)&R;
        float s = 0.f, s2 = 0.f;
#pragma unroll
        for (int e = 0; e < 4; ++e) {
            float mlo = med3(sg0 * bf_lo(u0[e]), sg1 * bf_lo(u1[e]), sg2 * bf_lo(u2[e]));
            float mhi = med3(sg0 * bf_hi(u0[e]), sg1 * bf_hi(u1[e]), sg2 * bf_hi(u2[e]));
            s  += mlo + mhi;
            s2 += mlo * mlo + mhi * mhi;
            rw[e] = (unsigned)f32_to_bf16(mlo) | ((unsigned)f32_to_bf16(mhi) << 16);
        }
        *(uint4*)(mpb + (size_t)c * HWn) = R;
#pragma unroll
        for (int o = 16; o > 0; o >>= 1) { s += __shfl_xor(s, o); s2 += __shfl_xor(s2, o); }
        if ((lane & 31) == 0) { atomicAdd(&stats[c], s); atomicAdd(&stats[128 + c], s2); }
    }
}

// ---- K3: out = relu(m*sc+sh) + x, with BN coefficients recomputed per block ----
// each block spans 1024 consecutive elements = a quarter of one channel's HW plane
__global__ __launch_bounds__(256) void k_apply(const unsigned short* __restrict__ m,
                                               const float* __restrict__ x,
                                               const float* __restrict__ stats,
                                               const float* __restrict__ gamma,
                                               const float* __restrict__ beta,
                                               float* __restrict__ out) {
    int i4 = blockIdx.x * 256 + threadIdx.x;      // 4,194,304 groups of 4
    size_t base = (size_t)i4 * 4;
    int c = (int)((base >> 12) & 127);
    const float N = 131072.f;
    float mean = stats[c] / N;
    float var  = stats[128 + c] / N - mean * mean;
    float sc   = gamma[c] * rsqrtf(var + 1e-5f);
    float sh   = beta[c] - mean * sc;
    ushort4 mv = ((const ushort4*)m)[i4];
    float4  xv = ((const float4*)x)[i4];
    float4 o;
    o.x = fmaxf(bf16_to_f32(mv.x) * sc + sh, 0.f) + xv.x;
    o.y = fmaxf(bf16_to_f32(mv.y) * sc + sh, 0.f) + xv.y;
    o.z = fmaxf(bf16_to_f32(mv.z) * sc + sh, 0.f) + xv.z;
    o.w = fmaxf(bf16_to_f32(mv.w) * sc + sh, 0.f) + xv.w;
    ((float4*)out)[i4] = o;
}

extern "C" void kernel_launch(void* const* d_in, const int* in_sizes, int n_in,
                              void* d_out, int out_size, void* d_ws, size_t ws_size,
                              hipStream_t stream) {
    const float* x      = (const float*)d_in[0];
    const float* w2     = (const float*)d_in[2];
    const float* gamma2 = (const float*)d_in[5];
    const float* beta2  = (const float*)d_in[6];
    const float* hs     = (const float*)d_in[7];
    const float* ss     = (const float*)d_in[8];
    float* out = (float*)d_out;

    char* ws = (char*)d_ws;
    unsigned short* xT  = (unsigned short*)(ws + OFF_XT);
    unsigned short* wfp = (unsigned short*)(ws + OFF_WF);
    int*            idp = (int*)(ws + OFF_IDX);
    unsigned short* mp  = (unsigned short*)(ws + OFF_M);
    float*          st  = (float*)(ws + OFF_STATS);

    hipMemsetAsync(st, 0, 1024, stream);
    k_transpose<<<2048, 256, 0, stream>>>(x, xT);
    k_wsk<<<433, 256, 0, stream>>>(w2, hs, ss, wfp, idp);
    k_conv<<<512, 256, 0, stream>>>(xT, wfp, idp, ss, mp, st);
    k_apply<<<16384, 256, 0, stream>>>(mp, x, st, gamma2, beta2, out);
}

// Round 4
// 205.911 us; speedup vs baseline: 1.5483x; 1.4636x over previous
//
#include <hip/hip_runtime.h>
#include <stdint.h>

typedef __bf16 bf16x8 __attribute__((ext_vector_type(8)));
typedef float  f32x4  __attribute__((ext_vector_type(4)));

static constexpr int Bn = 32, Cn = 128, Hn = 64, Wn = 64, HWn = 4096;
static constexpr size_t OFF_XT    = 0;                       // 33,554,432 B (bf16 x, chunk-major NHWC)
static constexpr size_t OFF_WF    = 33554432;                // 221,184 B (B-fragment-ordered weights)
static constexpr size_t OFF_IDX   = 33775616;                // 1,536 B
static constexpr size_t OFF_M     = 33777152;                // 33,554,432 B (median result, bf16, NCHW)
static constexpr size_t OFF_STATS = 67331584;                // 16,384 B (16 shadow copies of [256] stats)

__device__ __forceinline__ unsigned short f32_to_bf16(float f) {
    union { float f; unsigned u; } v; v.f = f;
    unsigned u = v.u;
    return (unsigned short)((u + 0x7FFFu + ((u >> 16) & 1u)) >> 16);
}
__device__ __forceinline__ float bf16_to_f32(unsigned short h) {
    union { unsigned u; float f; } v; v.u = ((unsigned)h) << 16;
    return v.f;
}
__device__ __forceinline__ float bf_lo(unsigned w) {
    union { unsigned u; float f; } v; v.u = w << 16; return v.f;
}
__device__ __forceinline__ float bf_hi(unsigned w) {
    union { unsigned u; float f; } v; v.u = w & 0xffff0000u; return v.f;
}
__device__ __forceinline__ float med3(float z0, float z1, float z2) {
    float lo = fminf(z0, z1), hi = fmaxf(z0, z1);
    return fmaxf(lo, fminf(hi, z2));
}

// ---- K_prep: fused transpose (blocks 0..2047) + wsk (2048..2479) + idx/zero (2480) ----
__global__ __launch_bounds__(256) void k_prep(const float* __restrict__ x,
                                              unsigned short* __restrict__ xT,
                                              const float* __restrict__ w2,
                                              const float* __restrict__ hs,
                                              const float* __restrict__ ss,
                                              unsigned short* __restrict__ wf,
                                              int* __restrict__ idx,
                                              float* __restrict__ stats16) {
    int t = threadIdx.x;
    if (blockIdx.x < 2048) {
        // x NCHW fp32 -> xT[b][q][y][x][32ci] bf16 (chunk-major NHWC)
        __shared__ __align__(16) unsigned short sm[256 * 40];
        int blk = blockIdx.x;                 // b*64 + q*16 + pt
        int pt = blk & 15, q = (blk >> 4) & 3, b = blk >> 6;
        int p0 = pt * 256;
        const float* xp = x + ((size_t)(b * Cn + q * 32) * HWn) + p0 + t;
#pragma unroll
        for (int cil = 0; cil < 32; ++cil)
            sm[t * 40 + cil] = f32_to_bf16(xp[(size_t)cil * HWn]);
        __syncthreads();
        uint4* dst = (uint4*)(xT + ((size_t)(b * 4 + q) * HWn + p0) * 32);
#pragma unroll
        for (int pass = 0; pass < 4; ++pass) {
            int pix = pass * 64 + (t >> 2);
            int ch  = t & 3;
            dst[pix * 4 + ch] = *(const uint4*)(&sm[pix * 40 + ch * 8]);
        }
    } else if (blockIdx.x < 2480) {
        // sketched weights in MFMA B-fragment order
        // f = ((q*9+tp)*6+nt)*512 + lane*8 + jj holds B[k=(lane>>4)*8+jj][n=nt*16+(lane&15)]
        int f = (blockIdx.x - 2048) * 256 + t;   // 110592 total
        int jj   = f & 7;
        int lane = (f >> 3) & 63;
        int nt   = (f >> 9) % 6;
        int qt   = f / (512 * 6);
        int tp   = qt % 9;
        int q    = qt / 9;
        int k  = ((lane >> 4) << 3) + jj;
        int ci = q * 32 + k;
        int n  = nt * 16 + (lane & 15);
        int j = n >> 5, d = n & 31;
        float sum = 0.f;
        for (int c = 0; c < 128; ++c) {
            float g = hs[(j * 32 + d) * 128 + c];
            if (g != 0.f) sum += g * ss[j * 128 + c] * w2[(c * 128 + ci) * 9 + tp];
        }
        wf[f] = f32_to_bf16(sum);
    } else {
        // recover idx from one-hot hs + zero the shadow stats
        for (int i = t; i < 384; i += 256) {
            int j = i >> 7, c = i & 127;
            int found = 0;
            for (int d = 0; d < 32; ++d)
                if (hs[(j * 32 + d) * 128 + c] > 0.5f) found = d;
            idx[i] = found;
        }
        for (int i = t; i < 4096; i += 256) stats16[i] = 0.f;
    }
}

// ---- K2: conv(96ch) + unsketch + median3 + fused BN stats -> m (bf16, NCHW) ----
// grid 512 = b*16 + tile; tile = 4 rows x 64 cols; wave w owns row py=w.
// Main loop is the verified round-0 structure (no prefetch buffers -> no spill).
// Epilogue: y stored channel-major [96][264], median gather via ds_read_b128,
// dwordx4 m stores, per-channel stats to 16-way-shadowed atomics (contention /16).
__global__ __launch_bounds__(256, 2) void k_conv(const unsigned short* __restrict__ xT,
                                                 const unsigned short* __restrict__ wf,
                                                 const int* __restrict__ idx,
                                                 const float* __restrict__ ss,
                                                 unsigned short* __restrict__ m_out,
                                                 float* __restrict__ stats16) {
    // staging 396*40 = 15840 ushorts, aliased with y tile [96][264] = 25344 ushorts
    __shared__ __align__(16) unsigned short sm[25344];
    __shared__ int   idx_sh[384];
    __shared__ float ss_sh[384];
    int tid  = threadIdx.x;
    int blk  = blockIdx.x;
    int tile = blk & 15, b = blk >> 4;
    int ty0  = tile * 4;
    int wv   = tid >> 6, lane = tid & 63;
    int quad = lane >> 4, l15 = lane & 15;

    for (int i = tid; i < 384; i += 256) { idx_sh[i] = idx[i]; ss_sh[i] = ss[i]; }

    f32x4 acc[4][6];
#pragma unroll
    for (int a = 0; a < 4; ++a)
#pragma unroll
        for (int nb = 0; nb < 6; ++nb) acc[a][nb] = (f32x4){0.f, 0.f, 0.f, 0.f};

    const unsigned short* wl = wf + lane * 8;

    for (int q = 0; q < 4; ++q) {
        __syncthreads();
        // stage halo: 396 records (6 rows x 66 cols) of 32 ci (64 B each)
#pragma unroll
        for (int pass = 0; pass < 2; ++pass) {
            int r = tid + pass * 256;
            if (r < 396) {
                int hy = r / 66, hx = r - hy * 66;
                int gy = ty0 + hy - 1, gx = hx - 1;
                uint4* dst = (uint4*)(&sm[r * 40]);
                if (gy >= 0 && gy < 64 && gx >= 0 && gx < 64) {
                    const uint4* src = (const uint4*)(xT + ((size_t)(b * 4 + q) * HWn + gy * 64 + gx) * 32);
                    dst[0] = src[0]; dst[1] = src[1]; dst[2] = src[2]; dst[3] = src[3];
                } else {
                    uint4 z = {0u, 0u, 0u, 0u};
                    dst[0] = z; dst[1] = z; dst[2] = z; dst[3] = z;
                }
            }
        }
        __syncthreads();
#pragma unroll
        for (int tp = 0; tp < 9; ++tp) {
            int dy = tp / 3, dx = tp % 3;
            bf16x8 bfr[6];
            const unsigned short* wb = wl + (size_t)((q * 9 + tp) * 6) * 512;
#pragma unroll
            for (int nb = 0; nb < 6; ++nb)
                bfr[nb] = *(const bf16x8*)(wb + nb * 512);
            bf16x8 afr[4];
#pragma unroll
            for (int mq = 0; mq < 4; ++mq) {
                int off = ((wv + dy) * 66 + mq * 16 + l15 + dx) * 40 + quad * 8;
                afr[mq] = *(const bf16x8*)(&sm[off]);
            }
#pragma unroll
            for (int mq = 0; mq < 4; ++mq)
#pragma unroll
                for (int nb = 0; nb < 6; ++nb)
                    acc[mq][nb] = __builtin_amdgcn_mfma_f32_16x16x32_bf16(afr[mq], bfr[nb], acc[mq][nb], 0, 0, 0);
        }
    }
    __syncthreads();
    // y-dump: channel-major [ch][264] so the median gather vectorizes over pixels
#pragma unroll
    for (int mq = 0; mq < 4; ++mq)
#pragma unroll
        for (int nb = 0; nb < 6; ++nb) {
            int ch = nb * 16 + l15;
            int px = wv * 64 + mq * 16 + quad * 4;
            ushort4 v;
            v.x = f32_to_bf16(acc[mq][nb][0]);
            v.y = f32_to_bf16(acc[mq][nb][1]);
            v.z = f32_to_bf16(acc[mq][nb][2]);
            v.w = f32_to_bf16(acc[mq][nb][3]);
            *(ushort4*)(&sm[ch * 264 + px]) = v;
        }
    __syncthreads();
    // median-of-3 (8 px per b128 read) + coalesced store + shadowed per-channel stats
    int half = lane >> 5, p8 = lane & 31;
    unsigned short* mpb = m_out + (size_t)b * Cn * HWn + tile * 256 + p8 * 8;
    float* stp = stats16 + (blk & 15) * 256;
#pragma unroll 2
    for (int i = 0; i < 16; ++i) {
        int c = wv * 32 + i * 2 + half;        // 32 lanes share one channel
        int r0 = idx_sh[c], r1 = 32 + idx_sh[128 + c], r2 = 64 + idx_sh[256 + c];
        float sg0 = ss_sh[c], sg1 = ss_sh[128 + c], sg2 = ss_sh[256 + c];
        uint4 w0 = *(const uint4*)(&sm[r0 * 264 + p8 * 8]);
        uint4 w1 = *(const uint4*)(&sm[r1 * 264 + p8 * 8]);
        uint4 w2v = *(const uint4*)(&sm[r2 * 264 + p8 * 8]);
        const unsigned* u0 = (const unsigned*)&w0;
        const unsigned* u1 = (const unsigned*)&w1;
        const unsigned* u2 = (const unsigned*)&w2v;
        uint4 R;
        unsigned* rw = (unsigned*)&R;
        float s = 0.f, s2 = 0.f;
#pragma unroll
        for (int e = 0; e < 4; ++e) {
            float mlo = med3(sg0 * bf_lo(u0[e]), sg1 * bf_lo(u1[e]), sg2 * bf_lo(u2[e]));
            float mhi = med3(sg0 * bf_hi(u0[e]), sg1 * bf_hi(u1[e]), sg2 * bf_hi(u2[e]));
            s  += mlo + mhi;
            s2 += mlo * mlo + mhi * mhi;
            rw[e] = (unsigned)f32_to_bf16(mlo) | ((unsigned)f32_to_bf16(mhi) << 16);
        }
        *(uint4*)(mpb + (size_t)c * HWn) = R;
#pragma unroll
        for (int o = 16; o > 0; o >>= 1) { s += __shfl_xor(s, o); s2 += __shfl_xor(s2, o); }
        if ((lane & 31) == 0) { atomicAdd(&stp[c], s); atomicAdd(&stp[128 + c], s2); }
    }
}

// ---- K3: out = relu(m*sc+sh) + x; BN coefficients reduced from 16 shadows per block ----
__global__ __launch_bounds__(256) void k_apply(const unsigned short* __restrict__ m,
                                               const float* __restrict__ x,
                                               const float* __restrict__ stats16,
                                               const float* __restrict__ gamma,
                                               const float* __restrict__ beta,
                                               float* __restrict__ out) {
    int i4 = blockIdx.x * 256 + threadIdx.x;      // 4,194,304 groups of 4
    size_t base = (size_t)i4 * 4;
    int c = (int)((base >> 12) & 127);            // uniform within a block
    float S = 0.f, S2 = 0.f;
#pragma unroll
    for (int k = 0; k < 16; ++k) {
        S  += stats16[k * 256 + c];
        S2 += stats16[k * 256 + 128 + c];
    }
    const float N = 131072.f;
    float mean = S / N;
    float var  = S2 / N - mean * mean;
    float sc   = gamma[c] * rsqrtf(var + 1e-5f);
    float sh   = beta[c] - mean * sc;
    ushort4 mv = ((const ushort4*)m)[i4];
    float4  xv = ((const float4*)x)[i4];
    float4 o;
    o.x = fmaxf(bf16_to_f32(mv.x) * sc + sh, 0.f) + xv.x;
    o.y = fmaxf(bf16_to_f32(mv.y) * sc + sh, 0.f) + xv.y;
    o.z = fmaxf(bf16_to_f32(mv.z) * sc + sh, 0.f) + xv.z;
    o.w = fmaxf(bf16_to_f32(mv.w) * sc + sh, 0.f) + xv.w;
    ((float4*)out)[i4] = o;
}

extern "C" void kernel_launch(void* const* d_in, const int* in_sizes, int n_in,
                              void* d_out, int out_size, void* d_ws, size_t ws_size,
                              hipStream_t stream) {
    const float* x      = (const float*)d_in[0];
    const float* w2     = (const float*)d_in[2];
    const float* gamma2 = (const float*)d_in[5];
    const float* beta2  = (const float*)d_in[6];
    const float* hs     = (const float*)d_in[7];
    const float* ss     = (const float*)d_in[8];
    float* out = (float*)d_out;

    char* ws = (char*)d_ws;
    unsigned short* xT  = (unsigned short*)(ws + OFF_XT);
    unsigned short* wfp = (unsigned short*)(ws + OFF_WF);
    int*            idp = (int*)(ws + OFF_IDX);
    unsigned short* mp  = (unsigned short*)(ws + OFF_M);
    float*          st  = (float*)(ws + OFF_STATS);

    k_prep<<<2481, 256, 0, stream>>>(x, xT, w2, hs, ss, wfp, idp, st);
    k_conv<<<512, 256, 0, stream>>>(xT, wfp, idp, ss, mp, st);
    k_apply<<<16384, 256, 0, stream>>>(mp, x, st, gamma2, beta2, out);
}

// Round 5
// 191.943 us; speedup vs baseline: 1.6610x; 1.0728x over previous
//
#include <hip/hip_runtime.h>
#include <stdint.h>

typedef __bf16 bf16x8 __attribute__((ext_vector_type(8)));
typedef float  f32x4  __attribute__((ext_vector_type(4)));

static constexpr int Bn = 32, Cn = 128, Hn = 64, Wn = 64, HWn = 4096;
static constexpr size_t OFF_XT    = 0;                       // 33,554,432 B (bf16 x, chunk-major NHWC)
static constexpr size_t OFF_WF    = 33554432;                // 221,184 B (B-fragment-ordered weights)
static constexpr size_t OFF_IDX   = 33775616;                // 1,536 B
static constexpr size_t OFF_M     = 33777152;                // 33,554,432 B (median result, bf16, NCHW)
static constexpr size_t OFF_STATS = 67331584;                // 16,384 B (16 shadow copies of [256] stats)
static constexpr size_t OFF_ZERO  = 67347968;                // 128 B zero page (halo OOB source)

__device__ __forceinline__ unsigned short f32_to_bf16(float f) {
    union { float f; unsigned u; } v; v.f = f;
    unsigned u = v.u;
    return (unsigned short)((u + 0x7FFFu + ((u >> 16) & 1u)) >> 16);
}
__device__ __forceinline__ float bf16_to_f32(unsigned short h) {
    union { unsigned u; float f; } v; v.u = ((unsigned)h) << 16;
    return v.f;
}
__device__ __forceinline__ float bf_lo(unsigned w) {
    union { unsigned u; float f; } v; v.u = w << 16; return v.f;
}
__device__ __forceinline__ float bf_hi(unsigned w) {
    union { unsigned u; float f; } v; v.u = w & 0xffff0000u; return v.f;
}
__device__ __forceinline__ float med3(float z0, float z1, float z2) {
    float lo = fminf(z0, z1), hi = fmaxf(z0, z1);
    return fmaxf(lo, fminf(hi, z2));
}
// direct global->LDS DMA, 16 B per lane (dest = wave-uniform base + lane*16)
__device__ __forceinline__ void gload_lds16(const unsigned short* g, unsigned short* l) {
    __builtin_amdgcn_global_load_lds(
        (const __attribute__((address_space(1))) unsigned int*)(const void*)g,
        (__attribute__((address_space(3))) unsigned int*)(void*)l,
        16, 0, 0);
}

// ---- K_prep: wsk (blocks 0..431, runs FIRST) + idx/zero (432) + transpose (433..2480) ----
__global__ __launch_bounds__(256) void k_prep(const float* __restrict__ x,
                                              unsigned short* __restrict__ xT,
                                              const float* __restrict__ w2,
                                              const float* __restrict__ hs,
                                              const float* __restrict__ ss,
                                              unsigned short* __restrict__ wf,
                                              int* __restrict__ idx,
                                              float* __restrict__ stats16,
                                              float* __restrict__ zerop) {
    __shared__ __align__(16) unsigned char smraw[20480];
    int t = threadIdx.x;
    if (blockIdx.x < 432) {
        // sketched weights: per-block LDS idx table, then LDS-scan + sparse w2 gather.
        // f = ((q*9+tp)*6+nt)*512 + lane*8 + jj holds B[k=(lane>>4)*8+jj][n=nt*16+(lane&15)]
        int*   idxs = (int*)smraw;
        float* sss  = (float*)(smraw + 1536);
        for (int i = t; i < 384; i += 256) {
            int j = i >> 7, c = i & 127;
            int found = 0;
#pragma unroll
            for (int d = 0; d < 32; ++d)
                if (hs[(j * 32 + d) * 128 + c] > 0.5f) found = d;
            idxs[i] = found;
            sss[i]  = ss[i];
        }
        __syncthreads();
        int f = blockIdx.x * 256 + t;   // 110592 total
        int jj   = f & 7;
        int lane = (f >> 3) & 63;
        int nt   = (f >> 9) % 6;
        int qt   = f / (512 * 6);
        int tp   = qt % 9;
        int q    = qt / 9;
        int k  = ((lane >> 4) << 3) + jj;
        int ci = q * 32 + k;
        int n  = nt * 16 + (lane & 15);
        int j = n >> 5, d = n & 31;
        const int*   ij = idxs + j * 128;
        const float* sj = sss  + j * 128;
        float sum = 0.f;
        for (int c = 0; c < 128; ++c)
            if (ij[c] == d) sum += sj[c] * w2[(c * 128 + ci) * 9 + tp];
        wf[f] = f32_to_bf16(sum);
    } else if (blockIdx.x == 432) {
        // recover idx from one-hot hs + zero shadow stats + zero page
        for (int i = t; i < 384; i += 256) {
            int j = i >> 7, c = i & 127;
            int found = 0;
            for (int d = 0; d < 32; ++d)
                if (hs[(j * 32 + d) * 128 + c] > 0.5f) found = d;
            idx[i] = found;
        }
        for (int i = t; i < 4096; i += 256) stats16[i] = 0.f;
        if (t < 32) zerop[t] = 0.f;
    } else {
        // x NCHW fp32 -> xT[b][q][y][x][32ci] bf16 (chunk-major NHWC)
        unsigned short* sm = (unsigned short*)smraw;   // 256*40 ushorts = 20480 B
        int blk = blockIdx.x - 433;           // b*64 + q*16 + pt
        int pt = blk & 15, q = (blk >> 4) & 3, b = blk >> 6;
        int p0 = pt * 256;
        const float* xp = x + ((size_t)(b * Cn + q * 32) * HWn) + p0 + t;
#pragma unroll
        for (int cil = 0; cil < 32; ++cil)
            sm[t * 40 + cil] = f32_to_bf16(xp[(size_t)cil * HWn]);
        __syncthreads();
        uint4* dst = (uint4*)(xT + ((size_t)(b * 4 + q) * HWn + p0) * 32);
#pragma unroll
        for (int pass = 0; pass < 4; ++pass) {
            int pix = pass * 64 + (t >> 2);
            int ch  = t & 3;
            dst[pix * 4 + ch] = *(const uint4*)(&sm[pix * 40 + ch * 8]);
        }
    }
}

// ---- K2: conv(96ch) + unsketch + median3 + fused BN stats -> m (bf16, NCHW) ----
// grid 512 = b*16 + tile (grid-capped at 2 blocks/CU -> win must come from ILP).
// Staging: T3-minimum 2-phase pipeline. Double-buffered halo halves filled by
// global_load_lds (linear dest, 64 B/record); q+1's loads are issued BEFORE q's
// tap loop and drained by the q-end __syncthreads, so HBM/L2 latency hides under
// 36 MFMAs. Bank conflicts on afr reads handled per rule #21: linear LDS dest +
// inverse-swizzled global SOURCE (cl = (k&3)^((r>>1)&3)) + same XOR on the READ
// (byte ^= ((byte>>7)&3)<<4) -> 2-way banks (free). OOB halo lanes read a zero page.
__global__ __launch_bounds__(256, 2) void k_conv(const unsigned short* __restrict__ xT,
                                                 const unsigned short* __restrict__ wf,
                                                 const int* __restrict__ idx,
                                                 const float* __restrict__ ss,
                                                 unsigned short* __restrict__ m_out,
                                                 float* __restrict__ stats16,
                                                 const unsigned short* __restrict__ zerop) {
    // two staging halves of 396*32 = 12672 ushorts each, aliased with y [96][264] = 25344
    __shared__ __align__(16) unsigned short sm[25344];
    __shared__ int   idx_sh[384];
    __shared__ float ss_sh[384];
    int tid  = threadIdx.x;
    int blk  = blockIdx.x;
    int tile = blk & 15, b = blk >> 4;
    int ty0  = tile * 4;
    int wv   = tid >> 6, lane = tid & 63;
    int quad = lane >> 4, l15 = lane & 15;

    for (int i = tid; i < 384; i += 256) { idx_sh[i] = idx[i]; ss_sh[i] = ss[i]; }

    // per-thread staging source offsets (ushort units from xq base), -1 = OOB/inactive
    int goff[7];
#pragma unroll
    for (int i = 0; i < 7; ++i) {
        int k = (i < 6) ? (tid + i * 256) : (tid + 1536);
        bool act = (i < 6) || (tid < 48);
        int r  = k >> 2;
        int cl = (k & 3) ^ ((r >> 1) & 3);          // inverse read-swizzle on the source
        int hy = r / 66, hx = r - hy * 66;
        int gy = ty0 + hy - 1, gx = hx - 1;
        goff[i] = (act && gy >= 0 && gy < 64 && gx >= 0 && gx < 64)
                ? ((gy * 64 + gx) * 32 + cl * 8) : -1;
    }

    f32x4 acc[4][6];
#pragma unroll
    for (int a = 0; a < 4; ++a)
#pragma unroll
        for (int nb = 0; nb < 6; ++nb) acc[a][nb] = (f32x4){0.f, 0.f, 0.f, 0.f};

    const unsigned short* wl = wf + lane * 8;

    // prologue: stage q=0 into half 0
    {
        const unsigned short* xq = xT + (size_t)(b * 4) * (HWn * 32);
#pragma unroll
        for (int i = 0; i < 6; ++i) {
            int k = tid + i * 256;
            gload_lds16((goff[i] >= 0) ? (xq + goff[i]) : zerop, &sm[k * 8]);
        }
        if (tid < 48) {
            int k = tid + 1536;
            gload_lds16((goff[6] >= 0) ? (xq + goff[6]) : zerop, &sm[k * 8]);
        }
    }
    __syncthreads();   // drains vmcnt before barrier -> half 0 ready

    for (int q = 0; q < 4; ++q) {
        unsigned short* cur = sm + (q & 1) * 12672;
        if (q < 3) {   // issue q+1 staging into the other half; latency hides under MFMAs
            const unsigned short* xq = xT + (size_t)(b * 4 + q + 1) * (HWn * 32);
            unsigned short* nxt = sm + ((q + 1) & 1) * 12672;
#pragma unroll
            for (int i = 0; i < 6; ++i) {
                int k = tid + i * 256;
                gload_lds16((goff[i] >= 0) ? (xq + goff[i]) : zerop, &nxt[k * 8]);
            }
            if (tid < 48) {
                int k = tid + 1536;
                gload_lds16((goff[6] >= 0) ? (xq + goff[6]) : zerop, &nxt[k * 8]);
            }
        }
#pragma unroll
        for (int tp = 0; tp < 9; ++tp) {
            int dy = tp / 3, dx = tp % 3;
            bf16x8 bfr[6];
            const unsigned short* wb = wl + (size_t)((q * 9 + tp) * 6) * 512;
#pragma unroll
            for (int nb = 0; nb < 6; ++nb)
                bfr[nb] = *(const bf16x8*)(wb + nb * 512);
            bf16x8 afr[4];
#pragma unroll
            for (int mq = 0; mq < 4; ++mq) {
                int pix = (wv + dy) * 66 + mq * 16 + l15 + dx;
                int byo = (pix << 6) + (quad << 4);
                byo ^= ((byo >> 7) & 3) << 4;        // read-side swizzle (matches source)
                afr[mq] = *(const bf16x8*)((const unsigned char*)cur + byo);
            }
#pragma unroll
            for (int mq = 0; mq < 4; ++mq)
#pragma unroll
                for (int nb = 0; nb < 6; ++nb)
                    acc[mq][nb] = __builtin_amdgcn_mfma_f32_16x16x32_bf16(afr[mq], bfr[nb], acc[mq][nb], 0, 0, 0);
        }
        __syncthreads();   // drains q+1 staging DMAs; next q reads the other half
    }

    // y-dump: channel-major [ch][264] so the median gather vectorizes over pixels
#pragma unroll
    for (int mq = 0; mq < 4; ++mq)
#pragma unroll
        for (int nb = 0; nb < 6; ++nb) {
            int ch = nb * 16 + l15;
            int px = wv * 64 + mq * 16 + quad * 4;
            ushort4 v;
            v.x = f32_to_bf16(acc[mq][nb][0]);
            v.y = f32_to_bf16(acc[mq][nb][1]);
            v.z = f32_to_bf16(acc[mq][nb][2]);
            v.w = f32_to_bf16(acc[mq][nb][3]);
            *(ushort4*)(&sm[ch * 264 + px]) = v;
        }
    __syncthreads();
    // median-of-3 (8 px per b128 read) + coalesced store + shadowed per-channel stats
    int half = lane >> 5, p8 = lane & 31;
    unsigned short* mpb = m_out + (size_t)b * Cn * HWn + tile * 256 + p8 * 8;
    float* stp = stats16 + (blk & 15) * 256;
#pragma unroll 2
    for (int i = 0; i < 16; ++i) {
        int c = wv * 32 + i * 2 + half;        // 32 lanes share one channel
        int r0 = idx_sh[c], r1 = 32 + idx_sh[128 + c], r2 = 64 + idx_sh[256 + c];
        float sg0 = ss_sh[c], sg1 = ss_sh[128 + c], sg2 = ss_sh[256 + c];
        uint4 w0 = *(const uint4*)(&sm[r0 * 264 + p8 * 8]);
        uint4 w1 = *(const uint4*)(&sm[r1 * 264 + p8 * 8]);
        uint4 w2v = *(const uint4*)(&sm[r2 * 264 + p8 * 8]);
        const unsigned* u0 = (const unsigned*)&w0;
        const unsigned* u1 = (const unsigned*)&w1;
        const unsigned* u2 = (const unsigned*)&w2v;
        uint4 R;
        unsigned* rw = (unsigned*)&R;
        float s = 0.f, s2 = 0.f;
#pragma unroll
        for (int e = 0; e < 4; ++e) {
            float mlo = med3(sg0 * bf_lo(u0[e]), sg1 * bf_lo(u1[e]), sg2 * bf_lo(u2[e]));
            float mhi = med3(sg0 * bf_hi(u0[e]), sg1 * bf_hi(u1[e]), sg2 * bf_hi(u2[e]));
            s  += mlo + mhi;
            s2 += mlo * mlo + mhi * mhi;
            rw[e] = (unsigned)f32_to_bf16(mlo) | ((unsigned)f32_to_bf16(mhi) << 16);
        }
        *(uint4*)(mpb + (size_t)c * HWn) = R;
#pragma unroll
        for (int o = 16; o > 0; o >>= 1) { s += __shfl_xor(s, o); s2 += __shfl_xor(s2, o); }
        if ((lane & 31) == 0) { atomicAdd(&stp[c], s); atomicAdd(&stp[128 + c], s2); }
    }
}

// ---- K3: out = relu(m*sc+sh) + x; BN coefficients reduced once per block (LDS) ----
__global__ __launch_bounds__(256) void k_apply(const unsigned short* __restrict__ m,
                                               const float* __restrict__ x,
                                               const float* __restrict__ stats16,
                                               const float* __restrict__ gamma,
                                               const float* __restrict__ beta,
                                               float* __restrict__ out) {
    __shared__ float co[2];
    int tid = threadIdx.x;
    int i4 = blockIdx.x * 256 + tid;              // 4,194,304 groups of 4
    int c = (blockIdx.x >> 2) & 127;              // block-uniform channel
    if (tid < 32) {
        float v = stats16[(tid & 15) * 256 + ((tid >> 4) << 7) + c];
#pragma unroll
        for (int o = 8; o > 0; o >>= 1) v += __shfl_xor(v, o);
        if ((tid & 15) == 0) co[tid >> 4] = v;
    }
    __syncthreads();
    const float N = 131072.f;
    float mean = co[0] / N;
    float var  = co[1] / N - mean * mean;
    float sc   = gamma[c] * rsqrtf(var + 1e-5f);
    float sh   = beta[c] - mean * sc;
    ushort4 mv = ((const ushort4*)m)[i4];
    float4  xv = ((const float4*)x)[i4];
    float4 o;
    o.x = fmaxf(bf16_to_f32(mv.x) * sc + sh, 0.f) + xv.x;
    o.y = fmaxf(bf16_to_f32(mv.y) * sc + sh, 0.f) + xv.y;
    o.z = fmaxf(bf16_to_f32(mv.z) * sc + sh, 0.f) + xv.z;
    o.w = fmaxf(bf16_to_f32(mv.w) * sc + sh, 0.f) + xv.w;
    ((float4*)out)[i4] = o;
}

extern "C" void kernel_launch(void* const* d_in, const int* in_sizes, int n_in,
                              void* d_out, int out_size, void* d_ws, size_t ws_size,
                              hipStream_t stream) {
    const float* x      = (const float*)d_in[0];
    const float* w2     = (const float*)d_in[2];
    const float* gamma2 = (const float*)d_in[5];
    const float* beta2  = (const float*)d_in[6];
    const float* hs     = (const float*)d_in[7];
    const float* ss     = (const float*)d_in[8];
    float* out = (float*)d_out;

    char* ws = (char*)d_ws;
    unsigned short* xT  = (unsigned short*)(ws + OFF_XT);
    unsigned short* wfp = (unsigned short*)(ws + OFF_WF);
    int*            idp = (int*)(ws + OFF_IDX);
    unsigned short* mp  = (unsigned short*)(ws + OFF_M);
    float*          st  = (float*)(ws + OFF_STATS);
    float*          zp  = (float*)(ws + OFF_ZERO);

    k_prep<<<2481, 256, 0, stream>>>(x, xT, w2, hs, ss, wfp, idp, st, zp);
    k_conv<<<512, 256, 0, stream>>>(xT, wfp, idp, ss, mp, st, (const unsigned short*)zp);
    k_apply<<<16384, 256, 0, stream>>>(mp, x, st, gamma2, beta2, out);
}